// Round 1
// baseline (980.925 us; speedup 1.0000x reference)
//
#include <hip/hip_runtime.h>
#include <math.h>

#define Bn 16
#define An 65472
#define Cn 81
#define Gn 50
#define ROWS 64
#define NBUCK 1024
#define LISTCAP 8192

static_assert((An % ROWS) == 0, "blocks never straddle batches");

constexpr float POS_THRESH_C = 0.5f;
constexpr float BETA_C = 1.0f / 9.0f;

typedef const __attribute__((address_space(1))) void GPTR;
typedef __attribute__((address_space(3))) void LPTR;

// ---------------- k0: zero accumulators + global bucket histogram ----------------
// grid = 65 blocks: block 64 zeroes scalars, blocks 0..63 zero ghist (64*256 = Bn*NBUCK)
__global__ __launch_bounds__(256) void k0_zero(int* __restrict__ numpos_b,
                                               float* __restrict__ fsums,
                                               int* __restrict__ ghist) {
    const int t = threadIdx.x;
    if (blockIdx.x == 64) {
        if (t < Bn) numpos_b[t] = 0;
        if (t == 32) { fsums[0] = 0.f; fsums[1] = 0.f; }
    } else {
        ghist[blockIdx.x * 256 + t] = 0;
    }
}

// ---------------- k1a: per-anchor best IoU over GT boxes ----------------
__global__ __launch_bounds__(256) void k1a(const float* __restrict__ anchors,
                                           const float* __restrict__ gts,
                                           const int* __restrict__ counts,
                                           float* __restrict__ best_iou,
                                           int* __restrict__ best_idx) {
    const int b = blockIdx.y;
    __shared__ float sg[Gn * 5];
    const int t = threadIdx.x;
    if (t < Gn * 5) sg[t] = gts[b * Gn * 5 + t];
    __syncthreads();
    const int a = blockIdx.x * 256 + t;
    if (a >= An) return;
    const int cnt = counts[b];
    const float4 av = ((const float4*)anchors)[a];
    const float area_a = (av.z - av.x) * (av.w - av.y);
    float best = -1.0f;
    int bidx = 0;
    for (int g = 0; g < Gn; ++g) {
        if (g >= cnt) break;
        const float bx0 = sg[g * 5 + 0], by0 = sg[g * 5 + 1];
        const float bx1 = sg[g * 5 + 2], by1 = sg[g * 5 + 3];
        const float w = fmaxf(fminf(av.z, bx1) - fmaxf(av.x, bx0), 0.f);
        const float h = fmaxf(fminf(av.w, by1) - fmaxf(av.y, by0), 0.f);
        const float inter = w * h;
        const float area_b = (bx1 - bx0) * (by1 - by0);
        const float iou = inter / (area_a + area_b - inter + 1e-10f);
        if (iou > best) { best = iou; bidx = g; }  // strict > keeps first (np argmax)
    }
    best_iou[(size_t)b * An + a] = best;
    best_idx[(size_t)b * An + a] = bidx;
}

// ---------------- k1b: per-(b,g) best anchor (argmax over axis 0) ----------------
__global__ __launch_bounds__(256) void k1b(const float* __restrict__ anchors,
                                           const float* __restrict__ gts,
                                           const int* __restrict__ counts,
                                           int* __restrict__ best_anchor) {
    const int b = blockIdx.y, g = blockIdx.x;
    const int t = threadIdx.x;
    const int cnt = counts[b];
    if (g >= cnt) { if (t == 0) best_anchor[b * Gn + g] = 0; return; }  // dropped by scatter
    const float bx0 = gts[(b * Gn + g) * 5 + 0], by0 = gts[(b * Gn + g) * 5 + 1];
    const float bx1 = gts[(b * Gn + g) * 5 + 2], by1 = gts[(b * Gn + g) * 5 + 3];
    const float area_b = (bx1 - bx0) * (by1 - by0);
    const float4* a4 = (const float4*)anchors;
    float best = -2.f;
    int bidx = 0x7fffffff;
    for (int base = t; base < An; base += 1024) {
        const int a1 = base + 256, a2 = base + 512, a3 = base + 768;
        const float4 av0 = a4[base];
        float4 av1, av2, av3;
        const bool ok1 = a1 < An, ok2 = a2 < An, ok3 = a3 < An;
        if (ok1) av1 = a4[a1];
        if (ok2) av2 = a4[a2];
        if (ok3) av3 = a4[a3];
        {
            const float area_a = (av0.z - av0.x) * (av0.w - av0.y);
            const float w = fmaxf(fminf(av0.z, bx1) - fmaxf(av0.x, bx0), 0.f);
            const float h = fmaxf(fminf(av0.w, by1) - fmaxf(av0.y, by0), 0.f);
            const float inter = w * h;
            const float iou = inter / (area_a + area_b - inter + 1e-10f);
            if (iou > best) { best = iou; bidx = base; }
        }
        if (ok1) {
            const float area_a = (av1.z - av1.x) * (av1.w - av1.y);
            const float w = fmaxf(fminf(av1.z, bx1) - fmaxf(av1.x, bx0), 0.f);
            const float h = fmaxf(fminf(av1.w, by1) - fmaxf(av1.y, by0), 0.f);
            const float inter = w * h;
            const float iou = inter / (area_a + area_b - inter + 1e-10f);
            if (iou > best) { best = iou; bidx = a1; }
        }
        if (ok2) {
            const float area_a = (av2.z - av2.x) * (av2.w - av2.y);
            const float w = fmaxf(fminf(av2.z, bx1) - fmaxf(av2.x, bx0), 0.f);
            const float h = fmaxf(fminf(av2.w, by1) - fmaxf(av2.y, by0), 0.f);
            const float inter = w * h;
            const float iou = inter / (area_a + area_b - inter + 1e-10f);
            if (iou > best) { best = iou; bidx = a2; }
        }
        if (ok3) {
            const float area_a = (av3.z - av3.x) * (av3.w - av3.y);
            const float w = fmaxf(fminf(av3.z, bx1) - fmaxf(av3.x, bx0), 0.f);
            const float h = fmaxf(fminf(av3.w, by1) - fmaxf(av3.y, by0), 0.f);
            const float inter = w * h;
            const float iou = inter / (area_a + area_b - inter + 1e-10f);
            if (iou > best) { best = iou; bidx = a3; }
        }
    }
    __shared__ float rv[256];
    __shared__ int ri[256];
    rv[t] = best; ri[t] = bidx;
    __syncthreads();
    for (int s = 128; s > 0; s >>= 1) {
        if (t < s) {
            const float fv = rv[t + s]; const int fi = ri[t + s];
            if (fv > rv[t] || (fv == rv[t] && fi < ri[t])) { rv[t] = fv; ri[t] = fi; }
        }
        __syncthreads();
    }
    if (t == 0) best_anchor[b * Gn + g] = ri[0];
}

// ---------------- k1c: sequential scatter (numpy last-write-wins) ----------------
__global__ __launch_bounds__(64) void k1c(const int* __restrict__ counts,
                                          const int* __restrict__ best_anchor,
                                          float* __restrict__ best_iou,
                                          int* __restrict__ best_idx) {
    const int b = threadIdx.x;
    if (b >= Bn) return;
    const int cnt = counts[b] < Gn ? counts[b] : Gn;
    for (int g = 0; g < cnt; ++g) {
        const int a = best_anchor[b * Gn + g];
        best_idx[(size_t)b * An + a] = g;
        best_iou[(size_t)b * An + a] = 2.0f;
    }
}

// ---------------- k2: one-pass LSE + losses + mining value + fused histogram ----
// ROWS=64 -> LDS 20.7KB -> 7 blocks/CU (28 waves, vs 3 blocks/12 waves before).
// An = 64*1023 so every block lies in exactly one batch.
__global__ __launch_bounds__(256, 7) void k2(const float* __restrict__ conf,
                                             const float* __restrict__ pred,
                                             const float* __restrict__ gts,
                                             const float* __restrict__ anchors,
                                             const float* __restrict__ best_iou,
                                             const int* __restrict__ best_idx,
                                             int* __restrict__ v_int,
                                             int* __restrict__ numpos_b,
                                             float* __restrict__ fsums,
                                             int* __restrict__ ghist) {
    __shared__ __align__(16) float sc[ROWS * Cn];   // 20736 B
    __shared__ float s_ce[4], s_loc[4];
    __shared__ int s_n[4];
    const int t = threadIdx.x;
    // async global->LDS staging, 16B chunks, lane-linear (wave-uniform base + lane*16)
    // ROWS*Cn = 5184 floats = 1296 16B chunks = 5*256 + 16
    {
        const float* gp = conf + (size_t)blockIdx.x * (ROWS * Cn);
#pragma unroll
        for (int k = 0; k < 5; ++k) {
            const int c = k * 256 + t;
            __builtin_amdgcn_global_load_lds((GPTR*)(gp + c * 4), (LPTR*)(sc + c * 4), 16, 0, 0);
        }
        if (t < 16) {
            const int c = 1280 + t;
            __builtin_amdgcn_global_load_lds((GPTR*)(gp + c * 4), (LPTR*)(sc + c * 4), 16, 0, 0);
        }
    }
    __syncthreads();
    const int r = t >> 2, h = t & 3;     // 4 lanes per row
    const float* row = sc + r * Cn;
    // j-ranges: h=0:[0,21) h=1:[21,41) h=2:[41,61) h=3:[61,81)
    const int j0 = h * 20 + (h != 0);
    const int j1 = 21 + h * 20;
    float s0 = 0.f, s1 = 0.f;
    for (int j = j0; j + 1 < j1; j += 2) { s0 += __expf(row[j]); s1 += __expf(row[j + 1]); }
    if (((j1 - j0) & 1) != 0) s0 += __expf(row[j1 - 1]);
    float s = s0 + s1;
    s += __shfl_xor(s, 1);
    s += __shfl_xor(s, 2);               // all 4 lanes hold full row sum
    const float lse = logf(s);

    float ce = 0.f, loc = 0.f;
    int n = 0;
    const int b = blockIdx.x / (An / ROWS);   // exact: blocks never straddle batches
    if (h == 0) {
        const size_t gidx = (size_t)blockIdx.x * ROWS + r;
        const int a = (int)(gidx - (size_t)b * An);
        const float bi = best_iou[gidx];
        const int idx = best_idx[gidx];
        if (bi < POS_THRESH_C) {
            const float v = lse - row[0];     // v = -logp0 > 0
            v_int[gidx] = __float_as_int(v);
            int bin = (int)(v * 64.0f);
            bin = bin < 0 ? 0 : (bin > NBUCK - 1 ? NBUCK - 1 : bin);
            atomicAdd(&ghist[b * NBUCK + bin], 1);   // fused k3a
        } else {
            v_int[gidx] = -1;  // positives excluded from mining
            int lab = (int)gts[((size_t)b * Gn + idx) * 5 + 4];
            lab = lab < 0 ? 0 : (lab > Cn - 1 ? Cn - 1 : lab);
            ce = lse - row[lab];
            n = 1;
            const float bx0 = gts[((size_t)b * Gn + idx) * 5 + 0];
            const float by0 = gts[((size_t)b * Gn + idx) * 5 + 1];
            const float bx1 = gts[((size_t)b * Gn + idx) * 5 + 2];
            const float by1 = gts[((size_t)b * Gn + idx) * 5 + 3];
            const float4 av = ((const float4*)anchors)[a];
            const float acx = (av.x + av.z) * 0.5f, acy = (av.y + av.w) * 0.5f;
            const float aw = av.z - av.x, ah = av.w - av.y;
            float tt[4];
            tt[0] = ((bx0 + bx1) * 0.5f - acx) / (aw * 0.1f);
            tt[1] = ((by0 + by1) * 0.5f - acy) / (ah * 0.1f);
            tt[2] = logf((bx1 - bx0) / aw + 1e-10f) / 0.2f;
            tt[3] = logf((by1 - by0) / ah + 1e-10f) / 0.2f;
            const float4 p = ((const float4*)pred)[gidx];
            const float pk[4] = {p.x, p.y, p.z, p.w};
#pragma unroll
            for (int k = 0; k < 4; ++k) {
                const float nn = fabsf(pk[k] - tt[k]);
                loc += (nn < BETA_C) ? 0.5f * nn * nn / BETA_C : nn - 0.5f * BETA_C;
            }
        }
    }
#pragma unroll
    for (int off = 32; off > 0; off >>= 1) {
        ce += __shfl_down(ce, off);
        loc += __shfl_down(loc, off);
        n += __shfl_down(n, off);
    }
    if ((t & 63) == 0) {
        const int w = t >> 6;
        s_ce[w] = ce; s_loc[w] = loc; s_n[w] = n;
    }
    __syncthreads();
    if (t == 0) {
        const float CE = s_ce[0] + s_ce[1] + s_ce[2] + s_ce[3];
        const float LC = s_loc[0] + s_loc[1] + s_loc[2] + s_loc[3];
        const int N = s_n[0] + s_n[1] + s_n[2] + s_n[3];
        if (CE != 0.f) atomicAdd(&fsums[0], CE);
        if (LC != 0.f) atomicAdd(&fsums[1], LC);
        if (N > 0) atomicAdd(&numpos_b[b], N);
    }
}

// ---------------- k3b: threshold bucket + exact top-K sum per batch ----------------
__global__ __launch_bounds__(256) void k3b(const int* __restrict__ v_int,
                                           const int* __restrict__ ghist,
                                           const int* __restrict__ numpos_b,
                                           float* __restrict__ neg_sum_b) {
    const int b = blockIdx.x, t = threadIdx.x;
    const int npb = numpos_b[b];
    const long long K = 3LL * npb;
    const int n_nonpos = An - npb;
    __shared__ int h[NBUCK];
    __shared__ int gsfx[256];
    __shared__ int s_kt, s_r, s_m;
    __shared__ float fred[256];
    __shared__ float list[LISTCAP];
    if (K <= 0) { if (t == 0) neg_sum_b[b] = 0.f; return; }
    const int4* v4 = (const int4*)(v_int + (size_t)b * An);
    const int N4 = An / 4;
    const bool selAll = (K >= n_nonpos);
    int kt = -1, r = 0;
    if (!selAll) {
        for (int i = t; i < NBUCK; i += 256) h[i] = ghist[b * NBUCK + i];
        if (t == 0) s_m = 0;
        __syncthreads();
        gsfx[t] = h[4 * t] + h[4 * t + 1] + h[4 * t + 2] + h[4 * t + 3];
        __syncthreads();
        if (t == 0) {  // suffix over 256 groups: gsfx[i] := count in groups > i
            int acc = 0;
            for (int i = 255; i >= 0; --i) { const int tmp = gsfx[i]; gsfx[i] = acc; acc += tmp; }
        }
        __syncthreads();
        {
            const int base = 4 * t;
            int cg[4];
            cg[3] = gsfx[t];
            cg[2] = cg[3] + h[base + 3];
            cg[1] = cg[2] + h[base + 2];
            cg[0] = cg[1] + h[base + 1];
#pragma unroll
            for (int q = 0; q < 4; ++q) {
                if (cg[q] < K && K <= cg[q] + (long long)h[base + q]) {
                    s_kt = base + q; s_r = (int)(K - cg[q]);
                }
            }
        }
        __syncthreads();
        kt = s_kt; r = s_r;
    } else {
        if (t == 0) s_m = 0;
        __syncthreads();
    }
    float s = 0.f;
    for (int i = t; i < N4; i += 256) {
        const int4 x4 = v4[i];
        const int xs[4] = {x4.x, x4.y, x4.z, x4.w};
#pragma unroll
        for (int q = 0; q < 4; ++q) {
            const int x = xs[q];
            if (x < 0) continue;
            const float v = __int_as_float(x);
            if (selAll) { s += v; continue; }
            int bin = (int)(v * 64.0f);
            bin = bin > NBUCK - 1 ? NBUCK - 1 : bin;
            if (bin > kt) s += v;
            else if (bin == kt) {
                const int p = atomicAdd(&s_m, 1);
                if (p < LISTCAP) list[p] = v;
            }
        }
    }
    __syncthreads();
    if (!selAll) {
        int M = s_m; M = M > LISTCAP ? LISTCAP : M;
        // exact tie-aware top-r: take x_i iff (#greater) + (#equal with smaller idx) < r
        for (int i = t; i < M; i += 256) {
            const float x = list[i];
            int cnt = 0;
            for (int j = 0; j < M; ++j) {
                const float y = list[j];
                cnt += (y > x) || (y == x && j < i);
            }
            if (cnt < r) s += x;
        }
    }
    fred[t] = s;
    __syncthreads();
    for (int st = 128; st > 0; st >>= 1) {
        if (t < st) fred[t] += fred[t + st];
        __syncthreads();
    }
    if (t == 0) neg_sum_b[b] = fred[0];
}

// ---------------- k4: combine ----------------
__global__ __launch_bounds__(64) void k4(const int* __restrict__ numpos_b,
                                         const float* __restrict__ fsums,
                                         const float* __restrict__ neg_sum_b,
                                         float* __restrict__ out) {
    if (threadIdx.x == 0) {
        int np = 0;
        for (int b = 0; b < Bn; ++b) np += numpos_b[b];
        const float num_pos = fmaxf(1.f, (float)np);
        const float denom = num_pos * 4.f;
        float neg = 0.f;
        for (int b = 0; b < Bn; ++b) neg += neg_sum_b[b];
        out[0] = fsums[1] / denom;           // localisation loss
        out[1] = (fsums[0] + neg) / denom;   // classification loss
    }
}

extern "C" void kernel_launch(void* const* d_in, const int* in_sizes, int n_in,
                              void* d_out, int out_size, void* d_ws, size_t ws_size,
                              hipStream_t stream) {
    const float* conf    = (const float*)d_in[0];
    const float* pred    = (const float*)d_in[1];
    const float* gts     = (const float*)d_in[2];
    const int*   counts  = (const int*)d_in[3];
    const float* anchors = (const float*)d_in[4];
    float* out = (float*)d_out;

    const size_t BA = (size_t)Bn * An;
    char* w = (char*)d_ws;
    float* best_iou    = (float*)w; w += BA * sizeof(float);
    int*   best_idx    = (int*)w;   w += BA * sizeof(int);
    int*   v_int       = (int*)w;   w += BA * sizeof(int);
    int*   best_anchor = (int*)w;   w += Bn * Gn * sizeof(int);
    int*   numpos_b    = (int*)w;   w += 64;
    float* fsums       = (float*)w; w += 64;   // [0]=ce_pos_sum [1]=loc_sum
    float* neg_sum_b   = (float*)w; w += 64;
    int*   ghist       = (int*)w;   w += Bn * NBUCK * sizeof(int);  // own buffer: k2 reads best_iou while updating hist

    hipLaunchKernelGGL(k0_zero, dim3(65), dim3(256), 0, stream, numpos_b, fsums, ghist);
    hipLaunchKernelGGL(k1a, dim3((An + 255) / 256, Bn), dim3(256), 0, stream,
                       anchors, gts, counts, best_iou, best_idx);
    hipLaunchKernelGGL(k1b, dim3(Gn, Bn), dim3(256), 0, stream,
                       anchors, gts, counts, best_anchor);
    hipLaunchKernelGGL(k1c, dim3(1), dim3(64), 0, stream,
                       counts, best_anchor, best_iou, best_idx);
    hipLaunchKernelGGL(k2, dim3((unsigned)(BA / ROWS)), dim3(256), 0, stream,
                       conf, pred, gts, anchors, best_iou, best_idx,
                       v_int, numpos_b, fsums, ghist);
    hipLaunchKernelGGL(k3b, dim3(Bn), dim3(256), 0, stream,
                       v_int, ghist, numpos_b, neg_sum_b);
    hipLaunchKernelGGL(k4, dim3(1), dim3(64), 0, stream, numpos_b, fsums, neg_sum_b, out);
}

// Round 2
// 935.439 us; speedup vs baseline: 1.0486x; 1.0486x over previous
//
#include <hip/hip_runtime.h>
#include <math.h>

#define Bn 16
#define An 65472
#define Cn 81
#define Gn 50
#define ROWS 64
#define NBUCK 1024
#define LISTCAP 8192

static_assert((An % ROWS) == 0, "blocks never straddle batches");

constexpr float POS_THRESH_C = 0.5f;
constexpr float BETA_C = 1.0f / 9.0f;

typedef const __attribute__((address_space(1))) void GPTR;
typedef __attribute__((address_space(3))) void LPTR;

// ---------------- k0: zero accumulators + global bucket histogram ----------------
// grid = 65 blocks: block 64 zeroes scalars, blocks 0..63 zero ghist (64*256 = Bn*NBUCK)
__global__ __launch_bounds__(256) void k0_zero(int* __restrict__ numpos_b,
                                               float* __restrict__ fsums,
                                               int* __restrict__ ghist) {
    const int t = threadIdx.x;
    if (blockIdx.x == 64) {
        if (t < Bn) numpos_b[t] = 0;
        if (t == 32) { fsums[0] = 0.f; fsums[1] = 0.f; }
    } else {
        ghist[blockIdx.x * 256 + t] = 0;
    }
}

// ---------------- k1a: per-anchor best IoU over GT boxes ----------------
__global__ __launch_bounds__(256) void k1a(const float* __restrict__ anchors,
                                           const float* __restrict__ gts,
                                           const int* __restrict__ counts,
                                           float* __restrict__ best_iou,
                                           int* __restrict__ best_idx) {
    const int b = blockIdx.y;
    __shared__ float sg[Gn * 5];
    const int t = threadIdx.x;
    if (t < Gn * 5) sg[t] = gts[b * Gn * 5 + t];
    __syncthreads();
    const int a = blockIdx.x * 256 + t;
    if (a >= An) return;
    const int cnt = counts[b];
    const float4 av = ((const float4*)anchors)[a];
    const float area_a = (av.z - av.x) * (av.w - av.y);
    float best = -1.0f;
    int bidx = 0;
    for (int g = 0; g < Gn; ++g) {
        if (g >= cnt) break;
        const float bx0 = sg[g * 5 + 0], by0 = sg[g * 5 + 1];
        const float bx1 = sg[g * 5 + 2], by1 = sg[g * 5 + 3];
        const float w = fmaxf(fminf(av.z, bx1) - fmaxf(av.x, bx0), 0.f);
        const float h = fmaxf(fminf(av.w, by1) - fmaxf(av.y, by0), 0.f);
        const float inter = w * h;
        const float area_b = (bx1 - bx0) * (by1 - by0);
        const float iou = inter / (area_a + area_b - inter + 1e-10f);
        if (iou > best) { best = iou; bidx = g; }  // strict > keeps first (np argmax)
    }
    best_iou[(size_t)b * An + a] = best;
    best_idx[(size_t)b * An + a] = bidx;
}

// ---------------- k1b: per-(b,g) best anchor (argmax over axis 0) ----------------
__global__ __launch_bounds__(256) void k1b(const float* __restrict__ anchors,
                                           const float* __restrict__ gts,
                                           const int* __restrict__ counts,
                                           int* __restrict__ best_anchor) {
    const int b = blockIdx.y, g = blockIdx.x;
    const int t = threadIdx.x;
    const int cnt = counts[b];
    if (g >= cnt) { if (t == 0) best_anchor[b * Gn + g] = 0; return; }  // dropped by scatter
    const float bx0 = gts[(b * Gn + g) * 5 + 0], by0 = gts[(b * Gn + g) * 5 + 1];
    const float bx1 = gts[(b * Gn + g) * 5 + 2], by1 = gts[(b * Gn + g) * 5 + 3];
    const float area_b = (bx1 - bx0) * (by1 - by0);
    const float4* a4 = (const float4*)anchors;
    float best = -2.f;
    int bidx = 0x7fffffff;
    for (int base = t; base < An; base += 1024) {
        const int a1 = base + 256, a2 = base + 512, a3 = base + 768;
        const float4 av0 = a4[base];
        float4 av1, av2, av3;
        const bool ok1 = a1 < An, ok2 = a2 < An, ok3 = a3 < An;
        if (ok1) av1 = a4[a1];
        if (ok2) av2 = a4[a2];
        if (ok3) av3 = a4[a3];
        {
            const float area_a = (av0.z - av0.x) * (av0.w - av0.y);
            const float w = fmaxf(fminf(av0.z, bx1) - fmaxf(av0.x, bx0), 0.f);
            const float h = fmaxf(fminf(av0.w, by1) - fmaxf(av0.y, by0), 0.f);
            const float inter = w * h;
            const float iou = inter / (area_a + area_b - inter + 1e-10f);
            if (iou > best) { best = iou; bidx = base; }
        }
        if (ok1) {
            const float area_a = (av1.z - av1.x) * (av1.w - av1.y);
            const float w = fmaxf(fminf(av1.z, bx1) - fmaxf(av1.x, bx0), 0.f);
            const float h = fmaxf(fminf(av1.w, by1) - fmaxf(av1.y, by0), 0.f);
            const float inter = w * h;
            const float iou = inter / (area_a + area_b - inter + 1e-10f);
            if (iou > best) { best = iou; bidx = a1; }
        }
        if (ok2) {
            const float area_a = (av2.z - av2.x) * (av2.w - av2.y);
            const float w = fmaxf(fminf(av2.z, bx1) - fmaxf(av2.x, bx0), 0.f);
            const float h = fmaxf(fminf(av2.w, by1) - fmaxf(av2.y, by0), 0.f);
            const float inter = w * h;
            const float iou = inter / (area_a + area_b - inter + 1e-10f);
            if (iou > best) { best = iou; bidx = a2; }
        }
        if (ok3) {
            const float area_a = (av3.z - av3.x) * (av3.w - av3.y);
            const float w = fmaxf(fminf(av3.z, bx1) - fmaxf(av3.x, bx0), 0.f);
            const float h = fmaxf(fminf(av3.w, by1) - fmaxf(av3.y, by0), 0.f);
            const float inter = w * h;
            const float iou = inter / (area_a + area_b - inter + 1e-10f);
            if (iou > best) { best = iou; bidx = a3; }
        }
    }
    __shared__ float rv[256];
    __shared__ int ri[256];
    rv[t] = best; ri[t] = bidx;
    __syncthreads();
    for (int s = 128; s > 0; s >>= 1) {
        if (t < s) {
            const float fv = rv[t + s]; const int fi = ri[t + s];
            if (fv > rv[t] || (fv == rv[t] && fi < ri[t])) { rv[t] = fv; ri[t] = fi; }
        }
        __syncthreads();
    }
    if (t == 0) best_anchor[b * Gn + g] = ri[0];
}

// ---------------- k1c: sequential scatter (numpy last-write-wins) ----------------
__global__ __launch_bounds__(64) void k1c(const int* __restrict__ counts,
                                          const int* __restrict__ best_anchor,
                                          float* __restrict__ best_iou,
                                          int* __restrict__ best_idx) {
    const int b = threadIdx.x;
    if (b >= Bn) return;
    const int cnt = counts[b] < Gn ? counts[b] : Gn;
    for (int g = 0; g < cnt; ++g) {
        const int a = best_anchor[b * Gn + g];
        best_idx[(size_t)b * An + a] = g;
        best_iou[(size_t)b * An + a] = 2.0f;
    }
}

// ---------------- k2: one-pass LSE + losses + mining value ----------------
// ROWS=64 -> LDS 20.7KB -> 7 blocks/CU (28 waves/CU) without forcing VGPR pressure.
// An = 64*1023 so every block lies in exactly one batch.
// NO global histogram atomics here (round-1 post-mortem: device-scope scattered
// atomics serialize at the cross-XCD coherence point, +26MB WRITE_SIZE, +225us).
__global__ __launch_bounds__(256) void k2(const float* __restrict__ conf,
                                          const float* __restrict__ pred,
                                          const float* __restrict__ gts,
                                          const float* __restrict__ anchors,
                                          const float* __restrict__ best_iou,
                                          const int* __restrict__ best_idx,
                                          int* __restrict__ v_int,
                                          int* __restrict__ numpos_b,
                                          float* __restrict__ fsums) {
    __shared__ __align__(16) float sc[ROWS * Cn];   // 20736 B
    __shared__ float s_ce[4], s_loc[4];
    __shared__ int s_n[4];
    const int t = threadIdx.x;
    // async global->LDS staging, 16B chunks, lane-linear (wave-uniform base + lane*16)
    // ROWS*Cn = 5184 floats = 1296 16B chunks = 5*256 + 16
    {
        const float* gp = conf + (size_t)blockIdx.x * (ROWS * Cn);
#pragma unroll
        for (int k = 0; k < 5; ++k) {
            const int c = k * 256 + t;
            __builtin_amdgcn_global_load_lds((GPTR*)(gp + c * 4), (LPTR*)(sc + c * 4), 16, 0, 0);
        }
        if (t < 16) {
            const int c = 1280 + t;
            __builtin_amdgcn_global_load_lds((GPTR*)(gp + c * 4), (LPTR*)(sc + c * 4), 16, 0, 0);
        }
    }
    __syncthreads();
    const int r = t >> 2, h = t & 3;     // 4 lanes per row
    const float* row = sc + r * Cn;
    // j-ranges: h=0:[0,21) h=1:[21,41) h=2:[41,61) h=3:[61,81)
    const int j0 = h * 20 + (h != 0);
    const int j1 = 21 + h * 20;
    float s0 = 0.f, s1 = 0.f;
    for (int j = j0; j + 1 < j1; j += 2) { s0 += __expf(row[j]); s1 += __expf(row[j + 1]); }
    if (((j1 - j0) & 1) != 0) s0 += __expf(row[j1 - 1]);
    float s = s0 + s1;
    s += __shfl_xor(s, 1);
    s += __shfl_xor(s, 2);               // all 4 lanes hold full row sum
    const float lse = logf(s);

    float ce = 0.f, loc = 0.f;
    int n = 0;
    const int b = blockIdx.x / (An / ROWS);   // exact: blocks never straddle batches
    if (h == 0) {
        const size_t gidx = (size_t)blockIdx.x * ROWS + r;
        const int a = (int)(gidx - (size_t)b * An);
        const float bi = best_iou[gidx];
        const int idx = best_idx[gidx];
        if (bi < POS_THRESH_C) {
            v_int[gidx] = __float_as_int(lse - row[0]);   // v = -logp0 >= 0
        } else {
            v_int[gidx] = -1;  // positives excluded from mining
            int lab = (int)gts[((size_t)b * Gn + idx) * 5 + 4];
            lab = lab < 0 ? 0 : (lab > Cn - 1 ? Cn - 1 : lab);
            ce = lse - row[lab];
            n = 1;
            const float bx0 = gts[((size_t)b * Gn + idx) * 5 + 0];
            const float by0 = gts[((size_t)b * Gn + idx) * 5 + 1];
            const float bx1 = gts[((size_t)b * Gn + idx) * 5 + 2];
            const float by1 = gts[((size_t)b * Gn + idx) * 5 + 3];
            const float4 av = ((const float4*)anchors)[a];
            const float acx = (av.x + av.z) * 0.5f, acy = (av.y + av.w) * 0.5f;
            const float aw = av.z - av.x, ah = av.w - av.y;
            float tt[4];
            tt[0] = ((bx0 + bx1) * 0.5f - acx) / (aw * 0.1f);
            tt[1] = ((by0 + by1) * 0.5f - acy) / (ah * 0.1f);
            tt[2] = logf((bx1 - bx0) / aw + 1e-10f) / 0.2f;
            tt[3] = logf((by1 - by0) / ah + 1e-10f) / 0.2f;
            const float4 p = ((const float4*)pred)[gidx];
            const float pk[4] = {p.x, p.y, p.z, p.w};
#pragma unroll
            for (int k = 0; k < 4; ++k) {
                const float nn = fabsf(pk[k] - tt[k]);
                loc += (nn < BETA_C) ? 0.5f * nn * nn / BETA_C : nn - 0.5f * BETA_C;
            }
        }
    }
#pragma unroll
    for (int off = 32; off > 0; off >>= 1) {
        ce += __shfl_down(ce, off);
        loc += __shfl_down(loc, off);
        n += __shfl_down(n, off);
    }
    if ((t & 63) == 0) {
        const int w = t >> 6;
        s_ce[w] = ce; s_loc[w] = loc; s_n[w] = n;
    }
    __syncthreads();
    if (t == 0) {
        const float CE = s_ce[0] + s_ce[1] + s_ce[2] + s_ce[3];
        const float LC = s_loc[0] + s_loc[1] + s_loc[2] + s_loc[3];
        const int N = s_n[0] + s_n[1] + s_n[2] + s_n[3];
        if (CE != 0.f) atomicAdd(&fsums[0], CE);
        if (LC != 0.f) atomicAdd(&fsums[1], LC);
        if (N > 0) atomicAdd(&numpos_b[b], N);
    }
}

// ---------------- k3a: per-chunk linear-bucket histogram ----------------
// LDS-combined histograms: same-bin pileup costs ~1cy in LDS (not a serialized
// RMW at the cross-XCD coherence point), and the global flush is ~100K atomics
// pre-combined ~4:1 across 256 blocks.
__global__ __launch_bounds__(256) void k3a(const int* __restrict__ v_int,
                                           int* __restrict__ ghist) {
    const int b = blockIdx.y, c = blockIdx.x;
    __shared__ int lh[NBUCK];
    const int t = threadIdx.x;
    for (int i = t; i < NBUCK; i += 256) lh[i] = 0;
    __syncthreads();
    const int4* v4 = (const int4*)(v_int + (size_t)b * An) + c * 1023;
    for (int i = t; i < 1023; i += 256) {
        const int4 x4 = v4[i];
        const int xs[4] = {x4.x, x4.y, x4.z, x4.w};
#pragma unroll
        for (int q = 0; q < 4; ++q) {
            const int x = xs[q];
            if (x < 0) continue;
            int bin = (int)(__int_as_float(x) * 64.0f);
            bin = bin > NBUCK - 1 ? NBUCK - 1 : bin;
            atomicAdd(&lh[bin], 1);
        }
    }
    __syncthreads();
    for (int i = t; i < NBUCK; i += 256) {
        const int cv = lh[i];
        if (cv) atomicAdd(&ghist[b * NBUCK + i], cv);
    }
}

// ---------------- k3b: threshold bucket + exact top-K sum per batch ----------------
__global__ __launch_bounds__(256) void k3b(const int* __restrict__ v_int,
                                           const int* __restrict__ ghist,
                                           const int* __restrict__ numpos_b,
                                           float* __restrict__ neg_sum_b) {
    const int b = blockIdx.x, t = threadIdx.x;
    const int npb = numpos_b[b];
    const long long K = 3LL * npb;
    const int n_nonpos = An - npb;
    __shared__ int h[NBUCK];
    __shared__ int gsfx[256];
    __shared__ int s_kt, s_r, s_m;
    __shared__ float fred[256];
    __shared__ float list[LISTCAP];
    if (K <= 0) { if (t == 0) neg_sum_b[b] = 0.f; return; }
    const int4* v4 = (const int4*)(v_int + (size_t)b * An);
    const int N4 = An / 4;
    const bool selAll = (K >= n_nonpos);
    int kt = -1, r = 0;
    if (!selAll) {
        for (int i = t; i < NBUCK; i += 256) h[i] = ghist[b * NBUCK + i];
        if (t == 0) s_m = 0;
        __syncthreads();
        gsfx[t] = h[4 * t] + h[4 * t + 1] + h[4 * t + 2] + h[4 * t + 3];
        __syncthreads();
        if (t == 0) {  // suffix over 256 groups: gsfx[i] := count in groups > i
            int acc = 0;
            for (int i = 255; i >= 0; --i) { const int tmp = gsfx[i]; gsfx[i] = acc; acc += tmp; }
        }
        __syncthreads();
        {
            const int base = 4 * t;
            int cg[4];
            cg[3] = gsfx[t];
            cg[2] = cg[3] + h[base + 3];
            cg[1] = cg[2] + h[base + 2];
            cg[0] = cg[1] + h[base + 1];
#pragma unroll
            for (int q = 0; q < 4; ++q) {
                if (cg[q] < K && K <= cg[q] + (long long)h[base + q]) {
                    s_kt = base + q; s_r = (int)(K - cg[q]);
                }
            }
        }
        __syncthreads();
        kt = s_kt; r = s_r;
    } else {
        if (t == 0) s_m = 0;
        __syncthreads();
    }
    float s = 0.f;
    for (int i = t; i < N4; i += 256) {
        const int4 x4 = v4[i];
        const int xs[4] = {x4.x, x4.y, x4.z, x4.w};
#pragma unroll
        for (int q = 0; q < 4; ++q) {
            const int x = xs[q];
            if (x < 0) continue;
            const float v = __int_as_float(x);
            if (selAll) { s += v; continue; }
            int bin = (int)(v * 64.0f);
            bin = bin > NBUCK - 1 ? NBUCK - 1 : bin;
            if (bin > kt) s += v;
            else if (bin == kt) {
                const int p = atomicAdd(&s_m, 1);
                if (p < LISTCAP) list[p] = v;
            }
        }
    }
    __syncthreads();
    if (!selAll) {
        int M = s_m; M = M > LISTCAP ? LISTCAP : M;
        // exact tie-aware top-r: take x_i iff (#greater) + (#equal with smaller idx) < r
        for (int i = t; i < M; i += 256) {
            const float x = list[i];
            int cnt = 0;
            for (int j = 0; j < M; ++j) {
                const float y = list[j];
                cnt += (y > x) || (y == x && j < i);
            }
            if (cnt < r) s += x;
        }
    }
    fred[t] = s;
    __syncthreads();
    for (int st = 128; st > 0; st >>= 1) {
        if (t < st) fred[t] += fred[t + st];
        __syncthreads();
    }
    if (t == 0) neg_sum_b[b] = fred[0];
}

// ---------------- k4: combine ----------------
__global__ __launch_bounds__(64) void k4(const int* __restrict__ numpos_b,
                                         const float* __restrict__ fsums,
                                         const float* __restrict__ neg_sum_b,
                                         float* __restrict__ out) {
    if (threadIdx.x == 0) {
        int np = 0;
        for (int b = 0; b < Bn; ++b) np += numpos_b[b];
        const float num_pos = fmaxf(1.f, (float)np);
        const float denom = num_pos * 4.f;
        float neg = 0.f;
        for (int b = 0; b < Bn; ++b) neg += neg_sum_b[b];
        out[0] = fsums[1] / denom;           // localisation loss
        out[1] = (fsums[0] + neg) / denom;   // classification loss
    }
}

extern "C" void kernel_launch(void* const* d_in, const int* in_sizes, int n_in,
                              void* d_out, int out_size, void* d_ws, size_t ws_size,
                              hipStream_t stream) {
    const float* conf    = (const float*)d_in[0];
    const float* pred    = (const float*)d_in[1];
    const float* gts     = (const float*)d_in[2];
    const int*   counts  = (const int*)d_in[3];
    const float* anchors = (const float*)d_in[4];
    float* out = (float*)d_out;

    const size_t BA = (size_t)Bn * An;
    char* w = (char*)d_ws;
    float* best_iou    = (float*)w; w += BA * sizeof(float);
    int*   best_idx    = (int*)w;   w += BA * sizeof(int);
    int*   v_int       = (int*)w;   w += BA * sizeof(int);
    int*   best_anchor = (int*)w;   w += Bn * Gn * sizeof(int);
    int*   numpos_b    = (int*)w;   w += 64;
    float* fsums       = (float*)w; w += 64;   // [0]=ce_pos_sum [1]=loc_sum
    float* neg_sum_b   = (float*)w; w += 64;
    int*   ghist       = (int*)w;   w += Bn * NBUCK * sizeof(int);

    hipLaunchKernelGGL(k0_zero, dim3(65), dim3(256), 0, stream, numpos_b, fsums, ghist);
    hipLaunchKernelGGL(k1a, dim3((An + 255) / 256, Bn), dim3(256), 0, stream,
                       anchors, gts, counts, best_iou, best_idx);
    hipLaunchKernelGGL(k1b, dim3(Gn, Bn), dim3(256), 0, stream,
                       anchors, gts, counts, best_anchor);
    hipLaunchKernelGGL(k1c, dim3(1), dim3(64), 0, stream,
                       counts, best_anchor, best_iou, best_idx);
    hipLaunchKernelGGL(k2, dim3((unsigned)(BA / ROWS)), dim3(256), 0, stream,
                       conf, pred, gts, anchors, best_iou, best_idx,
                       v_int, numpos_b, fsums);
    hipLaunchKernelGGL(k3a, dim3(16, Bn), dim3(256), 0, stream, v_int, ghist);
    hipLaunchKernelGGL(k3b, dim3(Bn), dim3(256), 0, stream,
                       v_int, ghist, numpos_b, neg_sum_b);
    hipLaunchKernelGGL(k4, dim3(1), dim3(64), 0, stream, numpos_b, fsums, neg_sum_b, out);
}

// Round 4
// 668.019 us; speedup vs baseline: 1.4684x; 1.4003x over previous
//
#include <hip/hip_runtime.h>
#include <math.h>

#define Bn 16
#define An 65472
#define Cn 81
#define Gn 50
#define ROWS 64        // rows per chunk
#define NCH 8          // chunks per k2 block (512 rows/block)
#define CHUNK_F4 1296  // float4s per chunk = ROWS*Cn/4
#define LD_T 216       // threads issuing DMA loads (216*6 = 1296)
#define LD_K 6         // DMA loads per issuing thread -> uniform 6 VMEM per wave
#define NCHH 4         // histogram chunks per batch in k3a
#define NBUCK 1024
#define LISTCAP 8192

static_assert((Bn * (long long)An) % (ROWS * NCH) == 0, "grid covers rows exactly");
static_assert(LD_T * LD_K == CHUNK_F4, "uniform load split");
static_assert((An / 4) % NCHH == 0, "hist chunks divide");

constexpr float POS_THRESH_C = 0.5f;
constexpr float BETA_C = 1.0f / 9.0f;

typedef const __attribute__((address_space(1))) void GPTR;
typedef __attribute__((address_space(3))) void LPTR;

// ---------------- k1a: per-anchor best IoU over GT boxes (+ scalar zero fold) ----
__global__ __launch_bounds__(256) void k1a(const float* __restrict__ anchors,
                                           const float* __restrict__ gts,
                                           const int* __restrict__ counts,
                                           float* __restrict__ best_iou,
                                           int* __restrict__ best_idx,
                                           int* __restrict__ numpos_b,
                                           float* __restrict__ fsums) {
    const int b = blockIdx.y;
    __shared__ float sg[Gn * 5];
    const int t = threadIdx.x;
    if (blockIdx.x == 0 && b == 0) {   // fold of old k0 scalar zeroing (k2 runs later)
        if (t < Bn) numpos_b[t] = 0;
        if (t == Bn) { fsums[0] = 0.f; fsums[1] = 0.f; }
    }
    if (t < Gn * 5) sg[t] = gts[b * Gn * 5 + t];
    __syncthreads();
    const int a = blockIdx.x * 256 + t;
    if (a >= An) return;
    const int cnt = counts[b];
    const float4 av = ((const float4*)anchors)[a];
    const float area_a = (av.z - av.x) * (av.w - av.y);
    float best = -1.0f;
    int bidx = 0;
    for (int g = 0; g < Gn; ++g) {
        if (g >= cnt) break;
        const float bx0 = sg[g * 5 + 0], by0 = sg[g * 5 + 1];
        const float bx1 = sg[g * 5 + 2], by1 = sg[g * 5 + 3];
        const float w = fmaxf(fminf(av.z, bx1) - fmaxf(av.x, bx0), 0.f);
        const float h = fmaxf(fminf(av.w, by1) - fmaxf(av.y, by0), 0.f);
        const float inter = w * h;
        const float area_b = (bx1 - bx0) * (by1 - by0);
        const float iou = inter / (area_a + area_b - inter + 1e-10f);
        if (iou > best) { best = iou; bidx = g; }  // strict > keeps first (np argmax)
    }
    best_iou[(size_t)b * An + a] = best;
    best_idx[(size_t)b * An + a] = bidx;
}

// ---------------- k1b: per-(b,g) best anchor (argmax over axis 0) ----------------
__global__ __launch_bounds__(256) void k1b(const float* __restrict__ anchors,
                                           const float* __restrict__ gts,
                                           const int* __restrict__ counts,
                                           int* __restrict__ best_anchor) {
    const int b = blockIdx.y, g = blockIdx.x;
    const int t = threadIdx.x;
    const int cnt = counts[b];
    if (g >= cnt) { if (t == 0) best_anchor[b * Gn + g] = 0; return; }  // dropped by scatter
    const float bx0 = gts[(b * Gn + g) * 5 + 0], by0 = gts[(b * Gn + g) * 5 + 1];
    const float bx1 = gts[(b * Gn + g) * 5 + 2], by1 = gts[(b * Gn + g) * 5 + 3];
    const float area_b = (bx1 - bx0) * (by1 - by0);
    const float4* a4 = (const float4*)anchors;
    float best = -2.f;
    int bidx = 0x7fffffff;
    for (int base = t; base < An; base += 1024) {
        const int a1 = base + 256, a2 = base + 512, a3 = base + 768;
        const float4 av0 = a4[base];
        float4 av1, av2, av3;
        const bool ok1 = a1 < An, ok2 = a2 < An, ok3 = a3 < An;
        if (ok1) av1 = a4[a1];
        if (ok2) av2 = a4[a2];
        if (ok3) av3 = a4[a3];
        {
            const float area_a = (av0.z - av0.x) * (av0.w - av0.y);
            const float w = fmaxf(fminf(av0.z, bx1) - fmaxf(av0.x, bx0), 0.f);
            const float h = fmaxf(fminf(av0.w, by1) - fmaxf(av0.y, by0), 0.f);
            const float inter = w * h;
            const float iou = inter / (area_a + area_b - inter + 1e-10f);
            if (iou > best) { best = iou; bidx = base; }
        }
        if (ok1) {
            const float area_a = (av1.z - av1.x) * (av1.w - av1.y);
            const float w = fmaxf(fminf(av1.z, bx1) - fmaxf(av1.x, bx0), 0.f);
            const float h = fmaxf(fminf(av1.w, by1) - fmaxf(av1.y, by0), 0.f);
            const float inter = w * h;
            const float iou = inter / (area_a + area_b - inter + 1e-10f);
            if (iou > best) { best = iou; bidx = a1; }
        }
        if (ok2) {
            const float area_a = (av2.z - av2.x) * (av2.w - av2.y);
            const float w = fmaxf(fminf(av2.z, bx1) - fmaxf(av2.x, bx0), 0.f);
            const float h = fmaxf(fminf(av2.w, by1) - fmaxf(av2.y, by0), 0.f);
            const float inter = w * h;
            const float iou = inter / (area_a + area_b - inter + 1e-10f);
            if (iou > best) { best = iou; bidx = a2; }
        }
        if (ok3) {
            const float area_a = (av3.z - av3.x) * (av3.w - av3.y);
            const float w = fmaxf(fminf(av3.z, bx1) - fmaxf(av3.x, bx0), 0.f);
            const float h = fmaxf(fminf(av3.w, by1) - fmaxf(av3.y, by0), 0.f);
            const float inter = w * h;
            const float iou = inter / (area_a + area_b - inter + 1e-10f);
            if (iou > best) { best = iou; bidx = a3; }
        }
    }
    __shared__ float rv[256];
    __shared__ int ri[256];
    rv[t] = best; ri[t] = bidx;
    __syncthreads();
    for (int s = 128; s > 0; s >>= 1) {
        if (t < s) {
            const float fv = rv[t + s]; const int fi = ri[t + s];
            if (fv > rv[t] || (fv == rv[t] && fi < ri[t])) { rv[t] = fv; ri[t] = fi; }
        }
        __syncthreads();
    }
    if (t == 0) best_anchor[b * Gn + g] = ri[0];
}

// ---------------- k1c: sequential scatter (numpy last-write-wins) ----------------
__global__ __launch_bounds__(64) void k1c(const int* __restrict__ counts,
                                          const int* __restrict__ best_anchor,
                                          float* __restrict__ best_iou,
                                          int* __restrict__ best_idx) {
    const int b = threadIdx.x;
    if (b >= Bn) return;
    const int cnt = counts[b] < Gn ? counts[b] : Gn;
    for (int g = 0; g < cnt; ++g) {
        const int a = best_anchor[b * Gn + g];
        best_idx[(size_t)b * An + a] = g;
        best_iou[(size_t)b * An + a] = 2.0f;
    }
}

// ---------------- k2: pipelined LSE + losses + mining value ----------------
// Double-buffered 8-chunk pipeline, counted vmcnt (T3/T4-mini): prefetch of chunk
// c+1 stays in flight across the barrier; never drain vmcnt to 0 in the loop.
// vmcnt(6) is safe w.r.t. compute-phase VMEM: those ops are issued BEFORE the
// newest 6 staging loads, so waiting to depth 6 drains them too.
__global__ __launch_bounds__(256) void k2(const float* __restrict__ conf,
                                          const float* __restrict__ pred,
                                          const float* __restrict__ gts,
                                          const float* __restrict__ anchors,
                                          const float* __restrict__ best_iou,
                                          const int* __restrict__ best_idx,
                                          int* __restrict__ v_int,
                                          int* __restrict__ numpos_b,
                                          float* __restrict__ fsums) {
    __shared__ __align__(16) float sc[2][ROWS * Cn];   // 2 x 20736 B
    __shared__ float s_ce[4], s_loc[4];
    __shared__ int s_n0[4], s_n1[4];
    const int t = threadIdx.x;
    const size_t rowbase = (size_t)blockIdx.x * (ROWS * NCH);
    const float* gbase = conf + rowbase * Cn;

    // prologue: issue chunk 0 (6 VMEM per wave; every wave has active lanes t<216)
    if (t < LD_T) {
#pragma unroll
        for (int k = 0; k < LD_K; ++k) {
            const int c = k * LD_T + t;
            __builtin_amdgcn_global_load_lds((GPTR*)(gbase + c * 4), (LPTR*)(&sc[0][0] + c * 4), 16, 0, 0);
        }
    }

    const int bf = (int)(rowbase / An);   // block spans <= 2 batches (512 << An)
    const int r = t >> 2, h = t & 3;      // 4 lanes per row
    const int j0 = h * 20 + (h != 0);     // h=0:[0,21) h=1:[21,41) h=2:[41,61) h=3:[61,81)
    const int j1 = 21 + h * 20;
    float ce = 0.f, loc = 0.f;
    int n0 = 0, n1 = 0;

    for (int cc = 0; cc < NCH; ++cc) {
        if (cc + 1 < NCH) {
            // issue next chunk into the other half
            if (t < LD_T) {
                const float* gp = gbase + (size_t)(cc + 1) * (ROWS * Cn);
                float* lp = &sc[(cc + 1) & 1][0];
#pragma unroll
                for (int k = 0; k < LD_K; ++k) {
                    const int c = k * LD_T + t;
                    __builtin_amdgcn_global_load_lds((GPTR*)(gp + c * 4), (LPTR*)(lp + c * 4), 16, 0, 0);
                }
            }
            // counted wait: 6 newest (chunk cc+1) may remain in flight; chunk cc landed
            asm volatile("s_waitcnt vmcnt(6)" ::: "memory");
        } else {
            asm volatile("s_waitcnt vmcnt(0)" ::: "memory");
        }
        __builtin_amdgcn_sched_barrier(0);
        __builtin_amdgcn_s_barrier();          // all waves passed their own vmcnt wait
        asm volatile("" ::: "memory");         // LDS reads below must not hoist above barrier

        const float* row = &sc[cc & 1][0] + r * Cn;
        float s0 = 0.f, s1 = 0.f;
        for (int j = j0; j + 1 < j1; j += 2) { s0 += __expf(row[j]); s1 += __expf(row[j + 1]); }
        if (((j1 - j0) & 1) != 0) s0 += __expf(row[j1 - 1]);
        float s = s0 + s1;
        s += __shfl_xor(s, 1);
        s += __shfl_xor(s, 2);                 // all 4 lanes hold full row sum
        const float lse = logf(s);

        if (h == 0) {
            const size_t gidx = rowbase + (size_t)cc * ROWS + r;
            const int b = (int)(gidx / An);
            const int a = (int)(gidx - (size_t)b * An);
            const float bi = best_iou[gidx];
            const int idx = best_idx[gidx];
            if (bi < POS_THRESH_C) {
                v_int[gidx] = __float_as_int(lse - row[0]);   // v = -logp0 >= 0
            } else {
                v_int[gidx] = -1;  // positives excluded from mining
                int lab = (int)gts[((size_t)b * Gn + idx) * 5 + 4];
                lab = lab < 0 ? 0 : (lab > Cn - 1 ? Cn - 1 : lab);
                ce += lse - row[lab];
                if (b == bf) ++n0; else ++n1;
                const float bx0 = gts[((size_t)b * Gn + idx) * 5 + 0];
                const float by0 = gts[((size_t)b * Gn + idx) * 5 + 1];
                const float bx1 = gts[((size_t)b * Gn + idx) * 5 + 2];
                const float by1 = gts[((size_t)b * Gn + idx) * 5 + 3];
                const float4 av = ((const float4*)anchors)[a];
                const float acx = (av.x + av.z) * 0.5f, acy = (av.y + av.w) * 0.5f;
                const float aw = av.z - av.x, ah = av.w - av.y;
                float tt[4];
                tt[0] = ((bx0 + bx1) * 0.5f - acx) / (aw * 0.1f);
                tt[1] = ((by0 + by1) * 0.5f - acy) / (ah * 0.1f);
                tt[2] = logf((bx1 - bx0) / aw + 1e-10f) / 0.2f;
                tt[3] = logf((by1 - by0) / ah + 1e-10f) / 0.2f;
                const float4 p = ((const float4*)pred)[gidx];
                const float pk[4] = {p.x, p.y, p.z, p.w};
#pragma unroll
                for (int k = 0; k < 4; ++k) {
                    const float nn = fabsf(pk[k] - tt[k]);
                    loc += (nn < BETA_C) ? 0.5f * nn * nn / BETA_C : nn - 0.5f * BETA_C;
                }
            }
        }
        asm volatile("" ::: "memory");         // compute reads done before release
        __builtin_amdgcn_s_barrier();          // half (cc&1) free for overwrite next iter
    }

    // single block-level reduction after all chunks
#pragma unroll
    for (int off = 32; off > 0; off >>= 1) {
        ce += __shfl_down(ce, off);
        loc += __shfl_down(loc, off);
        n0 += __shfl_down(n0, off);
        n1 += __shfl_down(n1, off);
    }
    if ((t & 63) == 0) {
        const int w = t >> 6;
        s_ce[w] = ce; s_loc[w] = loc; s_n0[w] = n0; s_n1[w] = n1;
    }
    __syncthreads();
    if (t == 0) {
        const float CE = s_ce[0] + s_ce[1] + s_ce[2] + s_ce[3];
        const float LC = s_loc[0] + s_loc[1] + s_loc[2] + s_loc[3];
        const int N0 = s_n0[0] + s_n0[1] + s_n0[2] + s_n0[3];
        const int N1 = s_n1[0] + s_n1[1] + s_n1[2] + s_n1[3];
        if (CE != 0.f) atomicAdd(&fsums[0], CE);
        if (LC != 0.f) atomicAdd(&fsums[1], LC);
        if (N0 > 0) atomicAdd(&numpos_b[bf], N0);
        if (N1 > 0) atomicAdd(&numpos_b[bf + 1], N1);   // N1>0 implies bf+1 <= 15
    }
}

// ---------------- k3a: per-chunk histogram, atomic-free flush ----------------
// Each (b, c) block writes its own NBUCK slot with plain stores: no pre-zero
// kernel, no global atomics. k3b sums the NCHH slots per bin.
// ghist aliases best_iou (dead after k2) -> zero workspace growth.
__global__ __launch_bounds__(256) void k3a(const int* __restrict__ v_int,
                                           int* __restrict__ ghist) {
    const int b = blockIdx.y, c = blockIdx.x;
    __shared__ int lh[NBUCK];
    const int t = threadIdx.x;
    for (int i = t; i < NBUCK; i += 256) lh[i] = 0;
    __syncthreads();
    const int CH4 = (An / 4) / NCHH;   // 4092 int4s per chunk
    const int4* v4 = (const int4*)(v_int + (size_t)b * An) + c * CH4;
    for (int i = t; i < CH4; i += 256) {
        const int4 x4 = v4[i];
        const int xs[4] = {x4.x, x4.y, x4.z, x4.w};
#pragma unroll
        for (int q = 0; q < 4; ++q) {
            const int x = xs[q];
            if (x < 0) continue;
            int bin = (int)(__int_as_float(x) * 64.0f);
            bin = bin > NBUCK - 1 ? NBUCK - 1 : bin;
            atomicAdd(&lh[bin], 1);
        }
    }
    __syncthreads();
    for (int i = t; i < NBUCK; i += 256)
        ghist[((size_t)(b * NCHH + c)) * NBUCK + i] = lh[i];
}

// ---------------- k3b: threshold bucket + exact top-K sum per batch ----------------
__global__ __launch_bounds__(256) void k3b(const int* __restrict__ v_int,
                                           const int* __restrict__ ghist,
                                           const int* __restrict__ numpos_b,
                                           float* __restrict__ neg_sum_b) {
    const int b = blockIdx.x, t = threadIdx.x;
    const int npb = numpos_b[b];
    const long long K = 3LL * npb;
    const int n_nonpos = An - npb;
    __shared__ int h[NBUCK];
    __shared__ int gsfx[256];
    __shared__ int s_kt, s_r, s_m;
    __shared__ float fred[256];
    __shared__ float list[LISTCAP];
    if (K <= 0) { if (t == 0) neg_sum_b[b] = 0.f; return; }
    const int4* v4 = (const int4*)(v_int + (size_t)b * An);
    const int N4 = An / 4;
    const bool selAll = (K >= n_nonpos);
    int kt = -1, r = 0;
    if (!selAll) {
        const int* gh = ghist + (size_t)(b * NCHH) * NBUCK;
        for (int i = t; i < NBUCK; i += 256) {
            int v = 0;
#pragma unroll
            for (int c = 0; c < NCHH; ++c) v += gh[c * NBUCK + i];
            h[i] = v;
        }
        if (t == 0) s_m = 0;
        __syncthreads();
        gsfx[t] = h[4 * t] + h[4 * t + 1] + h[4 * t + 2] + h[4 * t + 3];
        __syncthreads();
        if (t == 0) {  // suffix over 256 groups: gsfx[i] := count in groups > i
            int acc = 0;
            for (int i = 255; i >= 0; --i) { const int tmp = gsfx[i]; gsfx[i] = acc; acc += tmp; }
        }
        __syncthreads();
        {
            const int base = 4 * t;
            int cg[4];
            cg[3] = gsfx[t];
            cg[2] = cg[3] + h[base + 3];
            cg[1] = cg[2] + h[base + 2];
            cg[0] = cg[1] + h[base + 1];
#pragma unroll
            for (int q = 0; q < 4; ++q) {
                if (cg[q] < K && K <= cg[q] + (long long)h[base + q]) {
                    s_kt = base + q; s_r = (int)(K - cg[q]);
                }
            }
        }
        __syncthreads();
        kt = s_kt; r = s_r;
    } else {
        if (t == 0) s_m = 0;
        __syncthreads();
    }
    float s = 0.f;
    for (int i = t; i < N4; i += 256) {
        const int4 x4 = v4[i];
        const int xs[4] = {x4.x, x4.y, x4.z, x4.w};
#pragma unroll
        for (int q = 0; q < 4; ++q) {
            const int x = xs[q];
            if (x < 0) continue;
            const float v = __int_as_float(x);
            if (selAll) { s += v; continue; }
            int bin = (int)(v * 64.0f);
            bin = bin > NBUCK - 1 ? NBUCK - 1 : bin;
            if (bin > kt) s += v;
            else if (bin == kt) {
                const int p = atomicAdd(&s_m, 1);
                if (p < LISTCAP) list[p] = v;
            }
        }
    }
    __syncthreads();
    if (!selAll) {
        int M = s_m; M = M > LISTCAP ? LISTCAP : M;
        // exact tie-aware top-r: take x_i iff (#greater) + (#equal with smaller idx) < r
        for (int i = t; i < M; i += 256) {
            const float x = list[i];
            int cnt = 0;
            for (int j = 0; j < M; ++j) {
                const float y = list[j];
                cnt += (y > x) || (y == x && j < i);
            }
            if (cnt < r) s += x;
        }
    }
    fred[t] = s;
    __syncthreads();
    for (int st = 128; st > 0; st >>= 1) {
        if (t < st) fred[t] += fred[t + st];
        __syncthreads();
    }
    if (t == 0) neg_sum_b[b] = fred[0];
}

// ---------------- k4: combine ----------------
__global__ __launch_bounds__(64) void k4(const int* __restrict__ numpos_b,
                                         const float* __restrict__ fsums,
                                         const float* __restrict__ neg_sum_b,
                                         float* __restrict__ out) {
    if (threadIdx.x == 0) {
        int np = 0;
        for (int b = 0; b < Bn; ++b) np += numpos_b[b];
        const float num_pos = fmaxf(1.f, (float)np);
        const float denom = num_pos * 4.f;
        float neg = 0.f;
        for (int b = 0; b < Bn; ++b) neg += neg_sum_b[b];
        out[0] = fsums[1] / denom;           // localisation loss
        out[1] = (fsums[0] + neg) / denom;   // classification loss
    }
}

extern "C" void kernel_launch(void* const* d_in, const int* in_sizes, int n_in,
                              void* d_out, int out_size, void* d_ws, size_t ws_size,
                              hipStream_t stream) {
    const float* conf    = (const float*)d_in[0];
    const float* pred    = (const float*)d_in[1];
    const float* gts     = (const float*)d_in[2];
    const int*   counts  = (const int*)d_in[3];
    const float* anchors = (const float*)d_in[4];
    float* out = (float*)d_out;

    const size_t BA = (size_t)Bn * An;
    char* w = (char*)d_ws;
    float* best_iou    = (float*)w; w += BA * sizeof(float);
    int*   best_idx    = (int*)w;   w += BA * sizeof(int);
    int*   v_int       = (int*)w;   w += BA * sizeof(int);
    int*   best_anchor = (int*)w;   w += Bn * Gn * sizeof(int);
    int*   numpos_b    = (int*)w;   w += 64;
    float* fsums       = (float*)w; w += 64;   // [0]=ce_pos_sum [1]=loc_sum
    float* neg_sum_b   = (float*)w; w += 64;
    int*   ghist       = (int*)best_iou;       // dead after k2; needs 256KB of its 4MB

    hipLaunchKernelGGL(k1a, dim3((An + 255) / 256, Bn), dim3(256), 0, stream,
                       anchors, gts, counts, best_iou, best_idx, numpos_b, fsums);
    hipLaunchKernelGGL(k1b, dim3(Gn, Bn), dim3(256), 0, stream,
                       anchors, gts, counts, best_anchor);
    hipLaunchKernelGGL(k1c, dim3(1), dim3(64), 0, stream,
                       counts, best_anchor, best_iou, best_idx);
    hipLaunchKernelGGL(k2, dim3((unsigned)(BA / (ROWS * NCH))), dim3(256), 0, stream,
                       conf, pred, gts, anchors, best_iou, best_idx,
                       v_int, numpos_b, fsums);
    hipLaunchKernelGGL(k3a, dim3(NCHH, Bn), dim3(256), 0, stream, v_int, ghist);
    hipLaunchKernelGGL(k3b, dim3(Bn), dim3(256), 0, stream,
                       v_int, ghist, numpos_b, neg_sum_b);
    hipLaunchKernelGGL(k4, dim3(1), dim3(64), 0, stream, numpos_b, fsums, neg_sum_b, out);
}